// Round 6
// baseline (316.575 us; speedup 1.0000x reference)
//
#include <hip/hip_runtime.h>

#define N_NODES 100000
#define N_EDGES 1600000
#define NUM_G   4096
#define HID     128
#define F_IN    11
#define F_PAD   16
#define F_OUT   19

#define NB      256                  // dst buckets
#define KPB     391                  // nodes per bucket: 256*391 = 100096 >= 100000
#define P01_EPB 2048                 // edges per block in P0/P1

// ---------------- helpers ----------------
__device__ inline unsigned short f32_to_bf16_rne(float x) {
    unsigned int u = __float_as_uint(x);
    u = (u + 0x7fffu + ((u >> 16) & 1u)) >> 16;
    return (unsigned short)u;
}
__device__ inline float bf16_to_f32(unsigned short h) {
    return __uint_as_float(((unsigned int)h) << 16);
}

// ---------------- P0: global bucket histogram (gh pre-zeroed) ----------------
__global__ void p0_hist(const int* __restrict__ dst, int* __restrict__ gh) {
    __shared__ int h[NB];
    h[threadIdx.x] = 0;
    __syncthreads();
    int b0 = blockIdx.x * P01_EPB;
#pragma unroll
    for (int k = 0; k < 8; ++k) {
        int e = b0 + k * 256 + threadIdx.x;
        if (e < N_EDGES) atomicAdd(&h[dst[e] / KPB], 1);
    }
    __syncthreads();
    int c = h[threadIdx.x];
    if (c) atomicAdd(&gh[threadIdx.x], c);
}

// ---------------- exclusive scan of gh -> bbase, bcur ----------------
__global__ void p0_scan(const int* __restrict__ gh, int* __restrict__ bbase,
                        int* __restrict__ bcur) {
    __shared__ int tmp[NB];
    int i = threadIdx.x;
    int v = gh[i];
    tmp[i] = v;
    __syncthreads();
    for (int off = 1; off < NB; off <<= 1) {
        int t = (i >= off) ? tmp[i - off] : 0;
        __syncthreads();
        tmp[i] += t;
        __syncthreads();
    }
    bbase[i] = tmp[i] - v;
    bcur[i]  = tmp[i] - v;
    if (i == NB - 1) bbase[NB] = N_EDGES;
}

// ---------------- P1: scatter packed (src<<9 | dstLocal) into bucket regions ----------------
__global__ void p1_place(const int* __restrict__ src, const int* __restrict__ dst,
                         int* __restrict__ bcur, unsigned int* __restrict__ ebuf) {
    __shared__ int h[NB];
    __shared__ int base[NB];
    h[threadIdx.x] = 0;
    __syncthreads();
    unsigned int pk[8]; int bn[8];
    int b0 = blockIdx.x * P01_EPB;
#pragma unroll
    for (int k = 0; k < 8; ++k) {
        int e = b0 + k * 256 + threadIdx.x;
        if (e < N_EDGES) {
            int d = dst[e];
            bn[k] = d / KPB;
            pk[k] = ((unsigned)src[e] << 9) | (unsigned)(d - bn[k] * KPB);
        } else bn[k] = -1;
    }
#pragma unroll
    for (int k = 0; k < 8; ++k)
        if (bn[k] >= 0) atomicAdd(&h[bn[k]], 1);
    __syncthreads();
    {
        int c = h[threadIdx.x];
        base[threadIdx.x] = c ? atomicAdd(&bcur[threadIdx.x], c) : 0;
    }
    __syncthreads();
    h[threadIdx.x] = 0;            // reuse as local rank cursor
    __syncthreads();
#pragma unroll
    for (int k = 0; k < 8; ++k) {
        if (bn[k] >= 0) {
            int r = atomicAdd(&h[bn[k]], 1);
            ebuf[base[bn[k]] + r] = pk[k];
        }
    }
}

// ---------------- P2: per-bucket count + scan + fill col/wd + dinv + row_ptr ----------------
__global__ void p2_build(const unsigned int* __restrict__ ebuf, const int* __restrict__ bbase,
                         int* __restrict__ row_ptr, int* __restrict__ col,
                         float* __restrict__ wd, float* __restrict__ dinv) {
    __shared__ int hist[512];
    __shared__ int rp[512];
    __shared__ float ldinv[512];
    int b  = blockIdx.x;
    int t  = threadIdx.x;
    int dbase = b * KPB;
    int nd = N_NODES - dbase; if (nd > KPB) nd = KPB;
    hist[t] = 0;
    __syncthreads();
    int e0 = bbase[b], e1 = bbase[b + 1];
    for (int e = e0 + t; e < e1; e += 512)
        atomicAdd(&hist[ebuf[e] & 511u], 1);
    __syncthreads();
    int v = hist[t];
    rp[t] = v;
    __syncthreads();
    for (int off = 1; off < 512; off <<= 1) {
        int x = (t >= off) ? rp[t - off] : 0;
        __syncthreads();
        rp[t] += x;
        __syncthreads();
    }
    int excl = rp[t] - v;
    float di = rsqrtf(1.0f + (float)v);
    ldinv[t] = di;
    if (t < nd) {
        row_ptr[dbase + t] = e0 + excl;
        dinv[dbase + t]    = di;
    }
    if (b == NB - 1 && t == 0) row_ptr[N_NODES] = N_EDGES;
    __syncthreads();
    hist[t] = e0 + excl;           // reuse as col-position cursor
    __syncthreads();
    for (int e = e0 + t; e < e1; e += 512) {
        unsigned int w = ebuf[e];
        int dl = (int)(w & 511u);
        int pos = atomicAdd(&hist[dl], 1);
        col[pos] = (int)(w >> 9);
        wd[pos]  = ldinv[dl];      // dinv[dst] per edge, sequential
    }
}

// ---------------- prep: xp[v][0..15] = dinv[v]*x[v][f] (pad 11->16, 64B rows) ----------------
__global__ void prep_xp(const float* __restrict__ x, const float* __restrict__ dinv,
                        float* __restrict__ xp) {
    int i = blockIdx.x * 256 + threadIdx.x;
    if (i >= N_NODES * F_PAD) return;
    int v = i >> 4, f = i & 15;
    xp[i] = (f < F_IN) ? dinv[v] * x[v * F_IN + f] : 0.f;
}

// ---------------- layer-1 aggregate (unweighted row-sum of xp): xa_raw = xp[v] + sum xp[s] ----------------
__global__ void aggregate_x(const float4* __restrict__ xp4, const int* __restrict__ row_ptr,
                            const int* __restrict__ col, float4* __restrict__ xa4) {
    int tid  = threadIdx.x;
    int v    = blockIdx.x * 64 + (tid >> 2);     // 256 threads = 64 nodes
    int lane = tid & 3;                           // one float4 each, row = 64 B = 1 line
    if (v >= N_NODES) return;
    float4 acc = xp4[(size_t)v * 4 + lane];       // self-loop
    int j = row_ptr[v], end = row_ptr[v + 1];
    for (; j + 3 < end; j += 4) {
        int s0 = col[j], s1 = col[j + 1], s2 = col[j + 2], s3 = col[j + 3];
        float4 a0 = xp4[(size_t)s0 * 4 + lane];
        float4 a1 = xp4[(size_t)s1 * 4 + lane];
        float4 a2 = xp4[(size_t)s2 * 4 + lane];
        float4 a3 = xp4[(size_t)s3 * 4 + lane];
        acc.x += a0.x + a1.x + a2.x + a3.x;
        acc.y += a0.y + a1.y + a2.y + a3.y;
        acc.z += a0.z + a1.z + a2.z + a3.z;
        acc.w += a0.w + a1.w + a2.w + a3.w;
    }
    for (; j < end; ++j) {
        int s = col[j];
        float4 a0 = xp4[(size_t)s * 4 + lane];
        acc.x += a0.x; acc.y += a0.y; acc.z += a0.z; acc.w += a0.w;
    }
    xa4[(size_t)v * 4 + lane] = acc;
}

// ---------------- Bh' = bf16(dinv[v] * relu(dinv[v]*xa_raw@W1 + b1)) ----------------
__global__ void node_gemm1(const float* __restrict__ xa, const float* __restrict__ dinv,
                           const float* __restrict__ W1, const float* __restrict__ b1,
                           unsigned short* __restrict__ Bh) {
    __shared__ float xs[F_IN];
    int v = blockIdx.x;
    int j = threadIdx.x;
    if (j < F_IN) xs[j] = xa[(size_t)v * F_PAD + j];
    __syncthreads();
    float dv = dinv[v];
    float acc = 0.f;
#pragma unroll
    for (int k = 0; k < F_IN; ++k) acc += xs[k] * W1[k * HID + j];
    float h = fmaxf(dv * acc + b1[j], 0.f);
    Bh[(size_t)v * HID + j] = f32_to_bf16_rne(dv * h);
}

// ---------------- fused layer-2 aggregate + mean-pool + W2 + head (C never materialized) ----
// pooled_sum[g][f] = sum_{v in g} dinv[v]*Bh'[v][f] + sum_{e: dst in g} wd[e]*Bh'[col[e]][f]
__global__ void pool_head_fused(const unsigned short* __restrict__ Bh,
                                const float* __restrict__ dinv,
                                const int* __restrict__ row_ptr, const int* __restrict__ col,
                                const float* __restrict__ wd, const int* __restrict__ batch,
                                const float* __restrict__ W2, const float* __restrict__ b2,
                                const float* __restrict__ Wlin, const float* __restrict__ blin,
                                float* __restrict__ out) {
    __shared__ float r[HID];
    __shared__ float tt[HID];
    __shared__ int range[2];
    __shared__ int scol[256];
    __shared__ float swd[256];
    int g = blockIdx.x;
    int f = threadIdx.x;                 // 0..127
    if (f < 2) {
        int tgt = g + f;                 // lower_bound(batch, g) and (batch, g+1)
        int lo = 0, hi = N_NODES;
        while (lo < hi) { int m = (lo + hi) >> 1; if (batch[m] < tgt) lo = m + 1; else hi = m; }
        range[f] = lo;
    }
    __syncthreads();
    int r0 = range[0], r1 = range[1];
    float acc = 0.f;
    // self-loop terms (sequential rows)
    for (int v = r0; v < r1; ++v)
        acc += dinv[v] * bf16_to_f32(Bh[(size_t)v * HID + f]);
    // edge terms, LDS-staged in chunks of 256
    int e0 = row_ptr[r0], e1 = row_ptr[r1];
    for (int base = e0; base < e1; base += 256) {
        int n = e1 - base; if (n > 256) n = 256;
        if (f < n)       { scol[f] = col[base + f];             swd[f] = wd[base + f]; }
        int f2 = f + 128;
        if (f2 < n)      { scol[f2] = col[base + f2];           swd[f2] = wd[base + f2]; }
        __syncthreads();
        int k = 0;
        for (; k + 3 < n; k += 4) {
            int s0 = scol[k], s1 = scol[k+1], s2 = scol[k+2], s3 = scol[k+3];
            float w0 = swd[k], w1 = swd[k+1], w2 = swd[k+2], w3 = swd[k+3];
            float v0 = bf16_to_f32(Bh[(size_t)s0 * HID + f]);
            float v1 = bf16_to_f32(Bh[(size_t)s1 * HID + f]);
            float v2 = bf16_to_f32(Bh[(size_t)s2 * HID + f]);
            float v3 = bf16_to_f32(Bh[(size_t)s3 * HID + f]);
            acc += v0 * w0 + v1 * w1 + v2 * w2 + v3 * w3;
        }
        for (; k < n; ++k)
            acc += swd[k] * bf16_to_f32(Bh[(size_t)scol[k] * HID + f]);
        __syncthreads();
    }
    float cntv = (float)(r1 - r0);
    float inv  = (cntv > 0.f) ? 1.0f / cntv : 0.f;
    r[f] = acc * inv;
    __syncthreads();
    float bs = (cntv > 0.f) ? 1.0f : 0.f;
    float tj = b2[f] * bs;
#pragma unroll 8
    for (int k = 0; k < HID; ++k) tj += r[k] * W2[k * HID + f];
    tt[f] = tj;
    __syncthreads();
    if (f < F_OUT) {
        float o = blin[f];
#pragma unroll 8
        for (int k = 0; k < HID; ++k) o += tt[k] * Wlin[k * F_OUT + f];
        out[(size_t)g * F_OUT + f] = o;
    }
}

extern "C" void kernel_launch(void* const* d_in, const int* in_sizes, int n_in,
                              void* d_out, int out_size, void* d_ws, size_t ws_size,
                              hipStream_t stream) {
    const float* x    = (const float*)d_in[0];
    const int*   esrc = (const int*)  d_in[1];
    const int*   edst = (const int*)  d_in[2];
    const int*   batch= (const int*)  d_in[3];
    const float* W1   = (const float*)d_in[4];
    const float* b1   = (const float*)d_in[5];
    const float* W2   = (const float*)d_in[6];
    const float* b2   = (const float*)d_in[7];
    const float* Wlin = (const float*)d_in[8];
    const float* blin = (const float*)d_in[9];
    float* out = (float*)d_out;

    // workspace layout (~59 MB), 16B-aligned segments
    char* p = (char*)d_ws;
    float*          dinv    = (float*)p;          p += sizeof(float) * N_NODES;
    float*          xp      = (float*)p;          p += sizeof(float) * (size_t)N_NODES * F_PAD;
    float*          xa      = (float*)p;          p += sizeof(float) * (size_t)N_NODES * F_PAD;
    unsigned short* Bh      = (unsigned short*)p; p += sizeof(unsigned short) * (size_t)N_NODES * HID;
    unsigned int*   ebuf    = (unsigned int*)p;   p += sizeof(unsigned int) * (size_t)N_EDGES;
    int*            col     = (int*)p;            p += sizeof(int) * N_EDGES;
    float*          wd      = (float*)p;          p += sizeof(float) * N_EDGES;
    int*            row_ptr = (int*)p;            p += sizeof(int) * (N_NODES + 4);
    int*            gh      = (int*)p;            p += sizeof(int) * NB;
    int*            bbase   = (int*)p;            p += sizeof(int) * (NB + 4);
    int*            bcur    = (int*)p;            p += sizeof(int) * NB;

    const int nblk_e = (N_EDGES + P01_EPB - 1) / P01_EPB;   // 782

    // ---- CSR build (bucketed counting sort) + dinv + per-edge wd ----
    hipMemsetAsync(gh, 0, sizeof(int) * NB, stream);
    p0_hist <<<nblk_e, 256, 0, stream>>>(edst, gh);
    p0_scan <<<1, NB, 0, stream>>>(gh, bbase, bcur);
    p1_place<<<nblk_e, 256, 0, stream>>>(esrc, edst, bcur, ebuf);
    p2_build<<<NB, 512, 0, stream>>>(ebuf, bbase, row_ptr, col, wd, dinv);

    // ---- layer 1: xp = dinv*x (padded) ; xa_raw = rowsum ; Bh' = bf16(dinv*relu(dinv*xa@W1+b1))
    prep_xp<<<(N_NODES * F_PAD + 255) / 256, 256, 0, stream>>>(x, dinv, xp);
    aggregate_x<<<(N_NODES + 63) / 64, 256, 0, stream>>>((const float4*)xp, row_ptr, col,
                                                         (float4*)xa);
    node_gemm1<<<N_NODES, HID, 0, stream>>>(xa, dinv, W1, b1, Bh);

    // ---- fused layer-2 aggregate + mean-pool + W2 + b2 + Wlin + blin ----
    pool_head_fused<<<NUM_G, HID, 0, stream>>>(Bh, dinv, row_ptr, col, wd, batch,
                                               W2, b2, Wlin, blin, out);
}

// Round 7
// 293.658 us; speedup vs baseline: 1.0780x; 1.0780x over previous
//
#include <hip/hip_runtime.h>

#define N_NODES 100000
#define N_EDGES 1600000
#define NUM_G   4096
#define HID     128
#define F_IN    11
#define F_PAD   16
#define F_OUT   19

#define NB      256                  // dst buckets
#define KPB     391                  // nodes per bucket: 256*391 = 100096 >= 100000
#define P01_EPB 2048                 // edges per block in P0/P1

// ---------------- helpers ----------------
__device__ inline unsigned short f32_to_bf16_rne(float x) {
    unsigned int u = __float_as_uint(x);
    u = (u + 0x7fffu + ((u >> 16) & 1u)) >> 16;
    return (unsigned short)u;
}
__device__ inline float bf16_to_f32(unsigned short h) {
    return __uint_as_float(((unsigned int)h) << 16);
}
__device__ inline void bf16x8_to_f32(uint4 u, float f[8]) {
    f[0] = __uint_as_float(u.x << 16); f[1] = __uint_as_float(u.x & 0xffff0000u);
    f[2] = __uint_as_float(u.y << 16); f[3] = __uint_as_float(u.y & 0xffff0000u);
    f[4] = __uint_as_float(u.z << 16); f[5] = __uint_as_float(u.z & 0xffff0000u);
    f[6] = __uint_as_float(u.w << 16); f[7] = __uint_as_float(u.w & 0xffff0000u);
}

// ---------------- P0: global bucket histogram (gh pre-zeroed) ----------------
__global__ void p0_hist(const int* __restrict__ dst, int* __restrict__ gh) {
    __shared__ int h[NB];
    h[threadIdx.x] = 0;
    __syncthreads();
    int b0 = blockIdx.x * P01_EPB;
#pragma unroll
    for (int k = 0; k < 8; ++k) {
        int e = b0 + k * 256 + threadIdx.x;
        if (e < N_EDGES) atomicAdd(&h[dst[e] / KPB], 1);
    }
    __syncthreads();
    int c = h[threadIdx.x];
    if (c) atomicAdd(&gh[threadIdx.x], c);
}

// ---------------- exclusive scan of gh -> bbase, bcur ----------------
__global__ void p0_scan(const int* __restrict__ gh, int* __restrict__ bbase,
                        int* __restrict__ bcur) {
    __shared__ int tmp[NB];
    int i = threadIdx.x;
    int v = gh[i];
    tmp[i] = v;
    __syncthreads();
    for (int off = 1; off < NB; off <<= 1) {
        int t = (i >= off) ? tmp[i - off] : 0;
        __syncthreads();
        tmp[i] += t;
        __syncthreads();
    }
    bbase[i] = tmp[i] - v;
    bcur[i]  = tmp[i] - v;
    if (i == NB - 1) bbase[NB] = N_EDGES;
}

// ---------------- P1: scatter packed (src<<9 | dstLocal) into bucket regions ----------------
__global__ void p1_place(const int* __restrict__ src, const int* __restrict__ dst,
                         int* __restrict__ bcur, unsigned int* __restrict__ ebuf) {
    __shared__ int h[NB];
    __shared__ int base[NB];
    h[threadIdx.x] = 0;
    __syncthreads();
    unsigned int pk[8]; int bn[8];
    int b0 = blockIdx.x * P01_EPB;
#pragma unroll
    for (int k = 0; k < 8; ++k) {
        int e = b0 + k * 256 + threadIdx.x;
        if (e < N_EDGES) {
            int d = dst[e];
            bn[k] = d / KPB;
            pk[k] = ((unsigned)src[e] << 9) | (unsigned)(d - bn[k] * KPB);
        } else bn[k] = -1;
    }
#pragma unroll
    for (int k = 0; k < 8; ++k)
        if (bn[k] >= 0) atomicAdd(&h[bn[k]], 1);
    __syncthreads();
    {
        int c = h[threadIdx.x];
        base[threadIdx.x] = c ? atomicAdd(&bcur[threadIdx.x], c) : 0;
    }
    __syncthreads();
    h[threadIdx.x] = 0;            // reuse as local rank cursor
    __syncthreads();
#pragma unroll
    for (int k = 0; k < 8; ++k) {
        if (bn[k] >= 0) {
            int r = atomicAdd(&h[bn[k]], 1);
            ebuf[base[bn[k]] + r] = pk[k];
        }
    }
}

// ---------------- P2: per-bucket count + scan + fill col/wd + dinv + row_ptr ----------------
__global__ void p2_build(const unsigned int* __restrict__ ebuf, const int* __restrict__ bbase,
                         int* __restrict__ row_ptr, int* __restrict__ col,
                         float* __restrict__ wd, float* __restrict__ dinv) {
    __shared__ int hist[512];
    __shared__ int rp[512];
    __shared__ float ldinv[512];
    int b  = blockIdx.x;
    int t  = threadIdx.x;
    int dbase = b * KPB;
    int nd = N_NODES - dbase; if (nd > KPB) nd = KPB;
    hist[t] = 0;
    __syncthreads();
    int e0 = bbase[b], e1 = bbase[b + 1];
    for (int e = e0 + t; e < e1; e += 512)
        atomicAdd(&hist[ebuf[e] & 511u], 1);
    __syncthreads();
    int v = hist[t];
    rp[t] = v;
    __syncthreads();
    for (int off = 1; off < 512; off <<= 1) {
        int x = (t >= off) ? rp[t - off] : 0;
        __syncthreads();
        rp[t] += x;
        __syncthreads();
    }
    int excl = rp[t] - v;
    float di = rsqrtf(1.0f + (float)v);
    ldinv[t] = di;
    if (t < nd) {
        row_ptr[dbase + t] = e0 + excl;
        dinv[dbase + t]    = di;
    }
    if (b == NB - 1 && t == 0) row_ptr[N_NODES] = N_EDGES;
    __syncthreads();
    hist[t] = e0 + excl;           // reuse as col-position cursor
    __syncthreads();
    for (int e = e0 + t; e < e1; e += 512) {
        unsigned int w = ebuf[e];
        int dl = (int)(w & 511u);
        int pos = atomicAdd(&hist[dl], 1);
        col[pos] = (int)(w >> 9);
        wd[pos]  = ldinv[dl];      // dinv[dst] per edge, sequential
    }
}

// ---------------- prep: xp[v][0..15] = dinv[v]*x[v][f] (pad 11->16, 64B rows) ----------------
__global__ void prep_xp(const float* __restrict__ x, const float* __restrict__ dinv,
                        float* __restrict__ xp) {
    int i = blockIdx.x * 256 + threadIdx.x;
    if (i >= N_NODES * F_PAD) return;
    int v = i >> 4, f = i & 15;
    xp[i] = (f < F_IN) ? dinv[v] * x[v * F_IN + f] : 0.f;
}

// ---------------- layer-1 aggregate (unweighted row-sum of xp) ----------------
__global__ void aggregate_x(const float4* __restrict__ xp4, const int* __restrict__ row_ptr,
                            const int* __restrict__ col, float4* __restrict__ xa4) {
    int tid  = threadIdx.x;
    int v    = blockIdx.x * 64 + (tid >> 2);     // 256 threads = 64 nodes
    int lane = tid & 3;                           // one float4 each, row = 64 B = 1 line
    if (v >= N_NODES) return;
    float4 acc = xp4[(size_t)v * 4 + lane];       // self-loop
    int j = row_ptr[v], end = row_ptr[v + 1];
    for (; j + 3 < end; j += 4) {
        int s0 = col[j], s1 = col[j + 1], s2 = col[j + 2], s3 = col[j + 3];
        float4 a0 = xp4[(size_t)s0 * 4 + lane];
        float4 a1 = xp4[(size_t)s1 * 4 + lane];
        float4 a2 = xp4[(size_t)s2 * 4 + lane];
        float4 a3 = xp4[(size_t)s3 * 4 + lane];
        acc.x += a0.x + a1.x + a2.x + a3.x;
        acc.y += a0.y + a1.y + a2.y + a3.y;
        acc.z += a0.z + a1.z + a2.z + a3.z;
        acc.w += a0.w + a1.w + a2.w + a3.w;
    }
    for (; j < end; ++j) {
        int s = col[j];
        float4 a0 = xp4[(size_t)s * 4 + lane];
        acc.x += a0.x; acc.y += a0.y; acc.z += a0.z; acc.w += a0.w;
    }
    xa4[(size_t)v * 4 + lane] = acc;
}

// ---------------- Bh' = bf16(dinv[v] * relu(dinv[v]*xa_raw@W1 + b1)) ----------------
__global__ void node_gemm1(const float* __restrict__ xa, const float* __restrict__ dinv,
                           const float* __restrict__ W1, const float* __restrict__ b1,
                           unsigned short* __restrict__ Bh) {
    __shared__ float xs[F_IN];
    int v = blockIdx.x;
    int j = threadIdx.x;
    if (j < F_IN) xs[j] = xa[(size_t)v * F_PAD + j];
    __syncthreads();
    float dv = dinv[v];
    float acc = 0.f;
#pragma unroll
    for (int k = 0; k < F_IN; ++k) acc += xs[k] * W1[k * HID + j];
    float h = fmaxf(dv * acc + b1[j], 0.f);
    Bh[(size_t)v * HID + j] = f32_to_bf16_rne(dv * h);
}

// ---------------- fused layer-2 aggregate + mean-pool + W2 + head ----------------
// 256 thr = 16 groups x 16 lanes; lane owns 8 feats (uint4 load); group strides rows.
__global__ void pool_head_fused(const unsigned short* __restrict__ Bh,
                                const float* __restrict__ dinv,
                                const int* __restrict__ row_ptr, const int* __restrict__ col,
                                const float* __restrict__ wd, const int* __restrict__ batch,
                                const float* __restrict__ W2, const float* __restrict__ b2,
                                const float* __restrict__ Wlin, const float* __restrict__ blin,
                                float* __restrict__ out) {
    __shared__ float red[16][HID];       // 8 KB group-reduction scratch (reused for W2 partials)
    __shared__ float r[HID];
    __shared__ float tt[HID];
    __shared__ int range[2];
    int g    = blockIdx.x;
    int tid  = threadIdx.x;
    int grp  = tid >> 4;
    int lane = tid & 15;
    if (tid < 2) {
        int tgt = g + tid;               // lower_bound(batch, g) / (batch, g+1)
        int lo = 0, hi = N_NODES;
        while (lo < hi) { int m = (lo + hi) >> 1; if (batch[m] < tgt) lo = m + 1; else hi = m; }
        range[tid] = lo;
    }
    __syncthreads();
    int r0 = range[0], r1 = range[1];
    const uint4* B4 = (const uint4*)Bh;
    float acc[8];
#pragma unroll
    for (int k = 0; k < 8; ++k) acc[k] = 0.f;

    // self-loop terms: node v weight dinv[v]
    for (int v = r0 + grp; v < r1; v += 16) {
        float w = dinv[v];
        uint4 u = B4[(size_t)v * 16 + lane];
        float f8[8]; bf16x8_to_f32(u, f8);
#pragma unroll
        for (int k = 0; k < 8; ++k) acc[k] += f8[k] * w;
    }
    // edge terms: edge e weight wd[e], row Bh[col[e]]
    int e0 = row_ptr[r0], e1 = row_ptr[r1];
    int e = e0 + grp;
    for (; e + 16 < e1; e += 32) {       // unroll 2: keep two row loads in flight
        int   s0 = col[e],  s1 = col[e + 16];
        float w0 = wd[e],   w1 = wd[e + 16];
        uint4 u0 = B4[(size_t)s0 * 16 + lane];
        uint4 u1 = B4[(size_t)s1 * 16 + lane];
        float f0[8], f1[8];
        bf16x8_to_f32(u0, f0); bf16x8_to_f32(u1, f1);
#pragma unroll
        for (int k = 0; k < 8; ++k) acc[k] += f0[k] * w0 + f1[k] * w1;
    }
    if (e < e1) {
        int   s0 = col[e];
        float w0 = wd[e];
        uint4 u0 = B4[(size_t)s0 * 16 + lane];
        float f0[8]; bf16x8_to_f32(u0, f0);
#pragma unroll
        for (int k = 0; k < 8; ++k) acc[k] += f0[k] * w0;
    }
    // cross-group reduction
#pragma unroll
    for (int k = 0; k < 8; ++k) red[grp][lane * 8 + k] = acc[k];
    __syncthreads();
    float cntv = (float)(r1 - r0);
    float inv  = (cntv > 0.f) ? 1.0f / cntv : 0.f;
    if (tid < HID) {
        float s = 0.f;
#pragma unroll
        for (int q = 0; q < 16; ++q) s += red[q][tid];
        r[tid] = s * inv;
    }
    __syncthreads();
    // W2 dot, split-k over the two half-blocks
    {
        int f = tid & 127, half = tid >> 7;
        float tj = 0.f;
        int k0 = half * 64;
#pragma unroll 8
        for (int k = k0; k < k0 + 64; ++k) tj += r[k] * W2[k * HID + f];
        red[half][f] = tj;
    }
    __syncthreads();
    if (tid < HID) {
        float bs = (cntv > 0.f) ? 1.0f : 0.f;
        tt[tid] = red[0][tid] + red[1][tid] + b2[tid] * bs;
    }
    __syncthreads();
    if (tid < F_OUT) {
        float o = blin[tid];
#pragma unroll 8
        for (int k = 0; k < HID; ++k) o += tt[k] * Wlin[k * F_OUT + tid];
        out[(size_t)g * F_OUT + tid] = o;
    }
}

extern "C" void kernel_launch(void* const* d_in, const int* in_sizes, int n_in,
                              void* d_out, int out_size, void* d_ws, size_t ws_size,
                              hipStream_t stream) {
    const float* x    = (const float*)d_in[0];
    const int*   esrc = (const int*)  d_in[1];
    const int*   edst = (const int*)  d_in[2];
    const int*   batch= (const int*)  d_in[3];
    const float* W1   = (const float*)d_in[4];
    const float* b1   = (const float*)d_in[5];
    const float* W2   = (const float*)d_in[6];
    const float* b2   = (const float*)d_in[7];
    const float* Wlin = (const float*)d_in[8];
    const float* blin = (const float*)d_in[9];
    float* out = (float*)d_out;

    // workspace layout (~59 MB), 16B-aligned segments
    char* p = (char*)d_ws;
    float*          dinv    = (float*)p;          p += sizeof(float) * N_NODES;
    float*          xp      = (float*)p;          p += sizeof(float) * (size_t)N_NODES * F_PAD;
    float*          xa      = (float*)p;          p += sizeof(float) * (size_t)N_NODES * F_PAD;
    unsigned short* Bh      = (unsigned short*)p; p += sizeof(unsigned short) * (size_t)N_NODES * HID;
    unsigned int*   ebuf    = (unsigned int*)p;   p += sizeof(unsigned int) * (size_t)N_EDGES;
    int*            col     = (int*)p;            p += sizeof(int) * N_EDGES;
    float*          wd      = (float*)p;          p += sizeof(float) * N_EDGES;
    int*            row_ptr = (int*)p;            p += sizeof(int) * (N_NODES + 4);
    int*            gh      = (int*)p;            p += sizeof(int) * NB;
    int*            bbase   = (int*)p;            p += sizeof(int) * (NB + 4);
    int*            bcur    = (int*)p;            p += sizeof(int) * NB;

    const int nblk_e = (N_EDGES + P01_EPB - 1) / P01_EPB;   // 782

    // ---- CSR build (bucketed counting sort) + dinv + per-edge wd ----
    hipMemsetAsync(gh, 0, sizeof(int) * NB, stream);
    p0_hist <<<nblk_e, 256, 0, stream>>>(edst, gh);
    p0_scan <<<1, NB, 0, stream>>>(gh, bbase, bcur);
    p1_place<<<nblk_e, 256, 0, stream>>>(esrc, edst, bcur, ebuf);
    p2_build<<<NB, 512, 0, stream>>>(ebuf, bbase, row_ptr, col, wd, dinv);

    // ---- layer 1 ----
    prep_xp<<<(N_NODES * F_PAD + 255) / 256, 256, 0, stream>>>(x, dinv, xp);
    aggregate_x<<<(N_NODES + 63) / 64, 256, 0, stream>>>((const float4*)xp, row_ptr, col,
                                                         (float4*)xa);
    node_gemm1<<<N_NODES, HID, 0, stream>>>(xa, dinv, W1, b1, Bh);

    // ---- fused layer-2 aggregate + mean-pool + W2 + b2 + Wlin + blin ----
    pool_head_fused<<<NUM_G, 256, 0, stream>>>(Bh, dinv, row_ptr, col, wd, batch,
                                               W2, b2, Wlin, blin, out);
}

// Round 8
// 274.827 us; speedup vs baseline: 1.1519x; 1.0685x over previous
//
#include <hip/hip_runtime.h>

#define N_NODES 100000
#define N_EDGES 1600000
#define NUM_G   4096
#define HID     128
#define F_IN    11
#define F_PAD   16
#define F_OUT   19

#define NB      256                  // dst buckets
#define KPB     391                  // nodes per bucket: 256*391 = 100096 >= 100000
#define P01_EPB 2048                 // edges per block in P0/P1

// ---------------- helpers ----------------
__device__ inline unsigned short f32_to_bf16_rne(float x) {
    unsigned int u = __float_as_uint(x);
    u = (u + 0x7fffu + ((u >> 16) & 1u)) >> 16;
    return (unsigned short)u;
}
__device__ inline void bf16x8_to_f32(uint4 u, float f[8]) {
    f[0] = __uint_as_float(u.x << 16); f[1] = __uint_as_float(u.x & 0xffff0000u);
    f[2] = __uint_as_float(u.y << 16); f[3] = __uint_as_float(u.y & 0xffff0000u);
    f[4] = __uint_as_float(u.z << 16); f[5] = __uint_as_float(u.z & 0xffff0000u);
    f[6] = __uint_as_float(u.w << 16); f[7] = __uint_as_float(u.w & 0xffff0000u);
}

// ---------------- P0: global bucket histogram (gh pre-zeroed) ----------------
__global__ void p0_hist(const int* __restrict__ dst, int* __restrict__ gh) {
    __shared__ int h[NB];
    h[threadIdx.x] = 0;
    __syncthreads();
    int b0 = blockIdx.x * P01_EPB;
#pragma unroll
    for (int k = 0; k < 8; ++k) {
        int e = b0 + k * 256 + threadIdx.x;
        if (e < N_EDGES) atomicAdd(&h[dst[e] / KPB], 1);
    }
    __syncthreads();
    int c = h[threadIdx.x];
    if (c) atomicAdd(&gh[threadIdx.x], c);
}

// ---------------- exclusive scan of gh -> bbase, bcur ----------------
__global__ void p0_scan(const int* __restrict__ gh, int* __restrict__ bbase,
                        int* __restrict__ bcur) {
    __shared__ int tmp[NB];
    int i = threadIdx.x;
    int v = gh[i];
    tmp[i] = v;
    __syncthreads();
    for (int off = 1; off < NB; off <<= 1) {
        int t = (i >= off) ? tmp[i - off] : 0;
        __syncthreads();
        tmp[i] += t;
        __syncthreads();
    }
    bbase[i] = tmp[i] - v;
    bcur[i]  = tmp[i] - v;
    if (i == NB - 1) bbase[NB] = N_EDGES;
}

// ---------------- P1: scatter packed (src<<9 | dstLocal) into bucket regions ----------------
__global__ void p1_place(const int* __restrict__ src, const int* __restrict__ dst,
                         int* __restrict__ bcur, unsigned int* __restrict__ ebuf) {
    __shared__ int h[NB];
    __shared__ int base[NB];
    h[threadIdx.x] = 0;
    __syncthreads();
    unsigned int pk[8]; int bn[8];
    int b0 = blockIdx.x * P01_EPB;
#pragma unroll
    for (int k = 0; k < 8; ++k) {
        int e = b0 + k * 256 + threadIdx.x;
        if (e < N_EDGES) {
            int d = dst[e];
            bn[k] = d / KPB;
            pk[k] = ((unsigned)src[e] << 9) | (unsigned)(d - bn[k] * KPB);
        } else bn[k] = -1;
    }
#pragma unroll
    for (int k = 0; k < 8; ++k)
        if (bn[k] >= 0) atomicAdd(&h[bn[k]], 1);
    __syncthreads();
    {
        int c = h[threadIdx.x];
        base[threadIdx.x] = c ? atomicAdd(&bcur[threadIdx.x], c) : 0;
    }
    __syncthreads();
    h[threadIdx.x] = 0;            // reuse as local rank cursor
    __syncthreads();
#pragma unroll
    for (int k = 0; k < 8; ++k) {
        if (bn[k] >= 0) {
            int r = atomicAdd(&h[bn[k]], 1);
            ebuf[base[bn[k]] + r] = pk[k];
        }
    }
}

// ---------------- P2: per-bucket CSR build + dinv + wd + xp (prep fused) ----------------
__global__ void p2_build(const unsigned int* __restrict__ ebuf, const int* __restrict__ bbase,
                         const float* __restrict__ x,
                         int* __restrict__ row_ptr, int* __restrict__ col,
                         float* __restrict__ wd, float* __restrict__ dinv,
                         float* __restrict__ xp) {
    __shared__ int hist[512];
    __shared__ int rp[512];
    __shared__ float ldinv[512];
    int b  = blockIdx.x;
    int t  = threadIdx.x;
    int dbase = b * KPB;
    int nd = N_NODES - dbase; if (nd > KPB) nd = KPB;
    hist[t] = 0;
    __syncthreads();
    int e0 = bbase[b], e1 = bbase[b + 1];
    for (int e = e0 + t; e < e1; e += 512)
        atomicAdd(&hist[ebuf[e] & 511u], 1);
    __syncthreads();
    int v = hist[t];
    rp[t] = v;
    __syncthreads();
    for (int off = 1; off < 512; off <<= 1) {
        int xv = (t >= off) ? rp[t - off] : 0;
        __syncthreads();
        rp[t] += xv;
        __syncthreads();
    }
    int excl = rp[t] - v;
    float di = rsqrtf(1.0f + (float)v);
    ldinv[t] = di;
    if (t < nd) {
        row_ptr[dbase + t] = e0 + excl;
        dinv[dbase + t]    = di;
    }
    if (b == NB - 1 && t == 0) row_ptr[N_NODES] = N_EDGES;
    __syncthreads();
    hist[t] = e0 + excl;           // reuse as col-position cursor
    __syncthreads();
    for (int e = e0 + t; e < e1; e += 512) {
        unsigned int w = ebuf[e];
        int dl = (int)(w & 511u);
        int pos = atomicAdd(&hist[dl], 1);
        col[pos] = (int)(w >> 9);
        wd[pos]  = ldinv[dl];      // dinv[dst] per edge, sequential
    }
    // fused prep: xp[v][0..15] = dinv[v]*x[v][f] (pad 11->16)
    for (int idx = t; idx < nd * F_PAD; idx += 512) {
        int vl = idx >> 4, f = idx & 15;
        int gv = dbase + vl;
        xp[(size_t)gv * F_PAD + f] =
            (f < F_IN) ? ldinv[vl] * x[(size_t)gv * F_IN + f] : 0.f;
    }
}

// ---------------- fused layer-1 aggregate + W1-GEMM ----------------
// 256 thr, 64 nodes/block. Phase 1: gather rowsum of xp into LDS.
// Phase 2: Bh' = bf16(dinv * relu(dinv * xa @ W1 + b1)) from LDS.
__global__ void agg_gemm1(const float4* __restrict__ xp4, const int* __restrict__ row_ptr,
                          const int* __restrict__ col, const float* __restrict__ dinv,
                          const float* __restrict__ W1, const float* __restrict__ b1,
                          unsigned short* __restrict__ Bh) {
    __shared__ float xs[64][F_PAD];        // 4 KB
    __shared__ float W1s[F_IN * HID];      // 5.5 KB
    __shared__ float b1s[HID];
    __shared__ float ds[64];
    int tid = threadIdx.x;
    for (int i = tid; i < F_IN * HID; i += 256) W1s[i] = W1[i];
    if (tid < HID) b1s[tid] = b1[tid];
    int v0   = blockIdx.x * 64;
    int v    = v0 + (tid >> 2);
    int lane = tid & 3;
    if (v < N_NODES) {
        if (lane == 0) ds[tid >> 2] = dinv[v];
        float4 acc = xp4[(size_t)v * 4 + lane];        // self-loop
        int j = row_ptr[v], end = row_ptr[v + 1];
        for (; j + 3 < end; j += 4) {
            int s0 = col[j], s1 = col[j + 1], s2 = col[j + 2], s3 = col[j + 3];
            float4 a0 = xp4[(size_t)s0 * 4 + lane];
            float4 a1 = xp4[(size_t)s1 * 4 + lane];
            float4 a2 = xp4[(size_t)s2 * 4 + lane];
            float4 a3 = xp4[(size_t)s3 * 4 + lane];
            acc.x += a0.x + a1.x + a2.x + a3.x;
            acc.y += a0.y + a1.y + a2.y + a3.y;
            acc.z += a0.z + a1.z + a2.z + a3.z;
            acc.w += a0.w + a1.w + a2.w + a3.w;
        }
        for (; j < end; ++j) {
            int s = col[j];
            float4 a0 = xp4[(size_t)s * 4 + lane];
            acc.x += a0.x; acc.y += a0.y; acc.z += a0.z; acc.w += a0.w;
        }
        *(float4*)&xs[tid >> 2][lane * 4] = acc;
    }
    __syncthreads();
    // GEMM phase: feat j = tid&127, node n = (tid>>7) + 2*i
    int jf = tid & 127;
    int n0 = tid >> 7;
    int nmax = N_NODES - v0; if (nmax > 64) nmax = 64;
#pragma unroll 4
    for (int i = 0; i < 32; ++i) {
        int n = n0 + 2 * i;
        if (n < nmax) {
            float a = 0.f;
#pragma unroll
            for (int k = 0; k < F_IN; ++k) a += xs[n][k] * W1s[k * HID + jf];
            float dv = ds[n];
            float h = fmaxf(dv * a + b1s[jf], 0.f);
            Bh[(size_t)(v0 + n) * HID + jf] = f32_to_bf16_rne(dv * h);
        }
    }
}

// ---------------- fused layer-2 aggregate + mean-pool + W2 + head ----------------
// 256 thr = 16 groups x 16 lanes; lane owns 8 feats (uint4); unroll-4 row loads.
__global__ void pool_head_fused(const unsigned short* __restrict__ Bh,
                                const float* __restrict__ dinv,
                                const int* __restrict__ row_ptr, const int* __restrict__ col,
                                const float* __restrict__ wd, const int* __restrict__ batch,
                                const float* __restrict__ W2, const float* __restrict__ b2,
                                const float* __restrict__ Wlin, const float* __restrict__ blin,
                                float* __restrict__ out) {
    __shared__ float red[16][HID + 4];   // padded to break 8-float stride conflicts
    __shared__ float r[HID];
    __shared__ float tt[HID];
    __shared__ int range[2];
    int g    = blockIdx.x;
    int tid  = threadIdx.x;
    int grp  = tid >> 4;
    int lane = tid & 15;
    if (tid < 2) {
        int tgt = g + tid;
        int lo = 0, hi = N_NODES;
        while (lo < hi) { int m = (lo + hi) >> 1; if (batch[m] < tgt) lo = m + 1; else hi = m; }
        range[tid] = lo;
    }
    __syncthreads();
    int r0 = range[0], r1 = range[1];
    const uint4* B4 = (const uint4*)Bh;
    float acc[8];
#pragma unroll
    for (int k = 0; k < 8; ++k) acc[k] = 0.f;

    // self-loop terms
    for (int v = r0 + grp; v < r1; v += 16) {
        float w = dinv[v];
        uint4 u = B4[(size_t)v * 16 + lane];
        float f8[8]; bf16x8_to_f32(u, f8);
#pragma unroll
        for (int k = 0; k < 8; ++k) acc[k] += f8[k] * w;
    }
    // edge terms, unroll-4
    int e0 = row_ptr[r0], e1 = row_ptr[r1];
    int e = e0 + grp;
    for (; e + 48 < e1; e += 64) {
        int   s0 = col[e],      s1 = col[e + 16], s2 = col[e + 32], s3 = col[e + 48];
        float w0 = wd[e],       w1 = wd[e + 16],  w2 = wd[e + 32],  w3 = wd[e + 48];
        uint4 u0 = B4[(size_t)s0 * 16 + lane];
        uint4 u1 = B4[(size_t)s1 * 16 + lane];
        uint4 u2 = B4[(size_t)s2 * 16 + lane];
        uint4 u3 = B4[(size_t)s3 * 16 + lane];
        float f0[8], f1[8], f2[8], f3[8];
        bf16x8_to_f32(u0, f0); bf16x8_to_f32(u1, f1);
        bf16x8_to_f32(u2, f2); bf16x8_to_f32(u3, f3);
#pragma unroll
        for (int k = 0; k < 8; ++k)
            acc[k] += f0[k] * w0 + f1[k] * w1 + f2[k] * w2 + f3[k] * w3;
    }
    for (; e < e1; e += 16) {
        int   s0 = col[e];
        float w0 = wd[e];
        uint4 u0 = B4[(size_t)s0 * 16 + lane];
        float f0[8]; bf16x8_to_f32(u0, f0);
#pragma unroll
        for (int k = 0; k < 8; ++k) acc[k] += f0[k] * w0;
    }
    // cross-group reduction
#pragma unroll
    for (int k = 0; k < 8; ++k) red[grp][lane * 8 + k] = acc[k];
    __syncthreads();
    float cntv = (float)(r1 - r0);
    float inv  = (cntv > 0.f) ? 1.0f / cntv : 0.f;
    if (tid < HID) {
        float s = 0.f;
#pragma unroll
        for (int q = 0; q < 16; ++q) s += red[q][tid];
        r[tid] = s * inv;
    }
    __syncthreads();
    // W2 dot, split-k over the two half-blocks
    {
        int f = tid & 127, half = tid >> 7;
        float tj = 0.f;
        int k0 = half * 64;
#pragma unroll 8
        for (int k = k0; k < k0 + 64; ++k) tj += r[k] * W2[k * HID + f];
        red[half][f] = tj;
    }
    __syncthreads();
    if (tid < HID) {
        float bs = (cntv > 0.f) ? 1.0f : 0.f;
        tt[tid] = red[0][tid] + red[1][tid] + b2[tid] * bs;
    }
    __syncthreads();
    if (tid < F_OUT) {
        float o = blin[tid];
#pragma unroll 8
        for (int k = 0; k < HID; ++k) o += tt[k] * Wlin[k * F_OUT + tid];
        out[(size_t)g * F_OUT + tid] = o;
    }
}

extern "C" void kernel_launch(void* const* d_in, const int* in_sizes, int n_in,
                              void* d_out, int out_size, void* d_ws, size_t ws_size,
                              hipStream_t stream) {
    const float* x    = (const float*)d_in[0];
    const int*   esrc = (const int*)  d_in[1];
    const int*   edst = (const int*)  d_in[2];
    const int*   batch= (const int*)  d_in[3];
    const float* W1   = (const float*)d_in[4];
    const float* b1   = (const float*)d_in[5];
    const float* W2   = (const float*)d_in[6];
    const float* b2   = (const float*)d_in[7];
    const float* Wlin = (const float*)d_in[8];
    const float* blin = (const float*)d_in[9];
    float* out = (float*)d_out;

    // workspace layout (~53 MB), 16B-aligned segments
    char* p = (char*)d_ws;
    float*          dinv    = (float*)p;          p += sizeof(float) * N_NODES;
    float*          xp      = (float*)p;          p += sizeof(float) * (size_t)N_NODES * F_PAD;
    unsigned short* Bh      = (unsigned short*)p; p += sizeof(unsigned short) * (size_t)N_NODES * HID;
    unsigned int*   ebuf    = (unsigned int*)p;   p += sizeof(unsigned int) * (size_t)N_EDGES;
    int*            col     = (int*)p;            p += sizeof(int) * N_EDGES;
    float*          wd      = (float*)p;          p += sizeof(float) * N_EDGES;
    int*            row_ptr = (int*)p;            p += sizeof(int) * (N_NODES + 4);
    int*            gh      = (int*)p;            p += sizeof(int) * NB;
    int*            bbase   = (int*)p;            p += sizeof(int) * (NB + 4);
    int*            bcur    = (int*)p;            p += sizeof(int) * NB;

    const int nblk_e = (N_EDGES + P01_EPB - 1) / P01_EPB;   // 782

    // ---- CSR build (bucketed counting sort) + dinv + wd + xp ----
    hipMemsetAsync(gh, 0, sizeof(int) * NB, stream);
    p0_hist <<<nblk_e, 256, 0, stream>>>(edst, gh);
    p0_scan <<<1, NB, 0, stream>>>(gh, bbase, bcur);
    p1_place<<<nblk_e, 256, 0, stream>>>(esrc, edst, bcur, ebuf);
    p2_build<<<NB, 512, 0, stream>>>(ebuf, bbase, x, row_ptr, col, wd, dinv, xp);

    // ---- fused layer-1 aggregate + W1-GEMM ----
    agg_gemm1<<<(N_NODES + 63) / 64, 256, 0, stream>>>((const float4*)xp, row_ptr, col,
                                                       dinv, W1, b1, Bh);

    // ---- fused layer-2 aggregate + mean-pool + W2 + b2 + Wlin + blin ----
    pool_head_fused<<<NUM_G, 256, 0, stream>>>(Bh, dinv, row_ptr, col, wd, batch,
                                               W2, b2, Wlin, blin, out);
}